// Round 2
// baseline (2621.720 us; speedup 1.0000x reference)
//
#include <hip/hip_runtime.h>
#include <math.h>

// ---- problem constants ----
#define BSZ   4
#define NSEQ  512
#define NC    8       // C channels
#define DC    64      // per-column dim
#define DIM   512     // D = C*DC
#define EDIM  128     // MLP hidden
#define NBANK 8       // B
#define NSLOT 64      // M
#define VOC   32000
#define NROW  (BSZ*NSEQ)   // 2048
#define ETA_PM 0.1f
#define PCM_W  0.1f

// ---- helpers ----
__device__ __forceinline__ float wsum(float v){
#pragma unroll
  for (int m=1;m<64;m<<=1) v += __shfl_xor(v,m,64);
  return v;
}
__device__ __forceinline__ float sigm(float x){ return 1.f/(1.f+expf(-x)); }
__device__ __forceinline__ float gelu_f(float x){
  float x3 = x*x*x;
  return 0.5f*x*(1.f+tanhf(0.7978845608028654f*(x+0.044715f*x3)));
}

// ================= embed =================
__global__ __launch_bounds__(256) void k_embed(const int* __restrict__ ids,
    const float* __restrict__ emb, const float* __restrict__ pos,
    float* __restrict__ X, float* __restrict__ H){
  int bn = blockIdx.x;               // b*NSEQ+n
  int n  = bn & (NSEQ-1);
  int id = ids[bn];
  const float* e = emb + (size_t)id*DIM;
  const float* p = pos + (size_t)n*DIM;
  float* x = X + (size_t)bn*DIM;
  float* h = H + (size_t)bn*DIM;
  for (int d=threadIdx.x; d<DIM; d+=256){ float v = e[d]+p[d]; x[d]=v; h[d]=v; }
}

// ================= scan layer: LN + v,g =================
__global__ __launch_bounds__(512) void k_lnvg(const float* __restrict__ H,
    const float* __restrict__ Wv, const float* __restrict__ Wg,
    const float* __restrict__ lng, const float* __restrict__ lnb,
    float* __restrict__ Vb, float* __restrict__ Gb){
  __shared__ float wv[DC*DC];
  __shared__ float wg[DC*DC];
  __shared__ float hl[8][DC];
  int c    = blockIdx.x & 7;
  int tile = blockIdx.x >> 3;
  int w = threadIdx.x>>6, l = threadIdx.x&63;
  for (int i=threadIdx.x; i<DC*DC; i+=512){ wv[i]=Wv[c*DC*DC+i]; wg[i]=Wg[c*DC*DC+i]; }
  int bn = tile*8 + w;
  size_t idx = (size_t)bn*DIM + c*DC + l;
  float x = H[idx];
  float mu = wsum(x)*(1.f/64.f);
  float d0 = x-mu;
  float var = wsum(d0*d0)*(1.f/64.f);
  float h = d0*rsqrtf(var+1e-5f)*lng[l] + lnb[l];
  hl[w][l]=h;
  __syncthreads();
  float v=0.f,g=0.f;
#pragma unroll
  for (int d=0; d<DC; ++d){ float hd=hl[w][d]; v = fmaf(hd, wv[d*DC+l], v); g = fmaf(hd, wg[d*DC+l], g); }
  Vb[idx]=v; Gb[idx]=sigm(g);
}

// ================= gated linear scan, chunked 2-pass (block = one (b,c)) ====
__global__ __launch_bounds__(512) void k_scan(float* __restrict__ Vb, const float* __restrict__ alog){
  __shared__ float VW[8][64];
  int b = blockIdx.x>>3, c = blockIdx.x&7;
  int w = threadIdx.x>>6, e = threadIdx.x&63;
  float a = sigm(alog[c*DC+e]);
  float a2=a*a, a4=a2*a2, a8=a4*a4, a16=a8*a8, a32=a16*a16, a64=a32*a32;
  size_t base = ((size_t)(b*NSEQ + w*64)*NC + c)*DC + e;   // n = w*64+i, step 512 floats
  float s=0.f;
#pragma unroll 8
  for (int i=0;i<64;++i) s = fmaf(a, s, Vb[base + (size_t)i*512]);
  VW[w][e]=s;
  __syncthreads();
  float carry=0.f;
  for (int wp=0; wp<w; ++wp) carry = fmaf(carry, a64, VW[wp][e]);  // wave-uniform trip count
  s = carry;
#pragma unroll 8
  for (int i=0;i<64;++i){ size_t ix = base + (size_t)i*512; s = fmaf(a, s, Vb[ix]); Vb[ix]=s; }
}

// ================= scan layer: u=g*S, MLP, residual =================
__global__ __launch_bounds__(512) void k_mlp(float* __restrict__ H,
    const float* __restrict__ Sb, const float* __restrict__ Gb,
    const float* __restrict__ W1, const float* __restrict__ W2){
  __shared__ float w1[DC*EDIM];
  __shared__ float w2[EDIM*DC];
  __shared__ float ul[8][DC];
  __shared__ float tl[8][EDIM];
  int c    = blockIdx.x & 7;
  int tile = blockIdx.x >> 3;
  int w = threadIdx.x>>6, l = threadIdx.x&63;
  for (int i=threadIdx.x; i<DC*EDIM; i+=512){ w1[i]=W1[c*DC*EDIM+i]; w2[i]=W2[c*EDIM*DC+i]; }
  int bn = tile*8 + w;
  size_t idx = (size_t)bn*DIM + c*DC + l;
  float u = Sb[idx]*Gb[idx];
  ul[w][l]=u;
  __syncthreads();
  float t0=0.f,t1=0.f;
#pragma unroll
  for (int d=0; d<DC; ++d){ float ud=ul[w][d]; t0 = fmaf(ud, w1[d*EDIM+l], t0); t1 = fmaf(ud, w1[d*EDIM+64+l], t1); }
  tl[w][l]=gelu_f(t0); tl[w][64+l]=gelu_f(t1);
  float y=0.f;
#pragma unroll
  for (int e2=0; e2<EDIM; ++e2) y = fmaf(tl[w][e2], w2[e2*DC+l], y);
  H[idx] += y;
}

// ================= PCM + seed/w_cand heads (+ wc norm) =================
__global__ __launch_bounds__(512) void k_pcm(const float* __restrict__ X, float* __restrict__ H,
    const float* __restrict__ Wpred, const float* __restrict__ bpred, const float* __restrict__ Wgain,
    const float* __restrict__ Wsw, const float* __restrict__ bsw,
    float* __restrict__ TS, float* __restrict__ SEED, float* __restrict__ WC,
    float* __restrict__ WCN, float* __restrict__ auxp){
  __shared__ float hl[NC][DC];
  __shared__ float sl[NC][DC];
  __shared__ float auxl[NC];
  __shared__ float wcl[NC];
  int bn=blockIdx.x; int c=threadIdx.x>>6; int l=threadIdx.x&63;
  size_t idx=(size_t)bn*DIM + c*DC + l;
  float hv=H[idx], xv=X[idx];
  hl[c][l]=hv;
  const float* wp = Wpred + c*DC*DC;
  float z = bpred[c*DC+l];
#pragma unroll
  for (int d=0; d<DC; ++d) z = fmaf(hl[c][d], wp[d*DC+l], z);
  float sp = xv - z;
  float aw = wsum(sp*sp);
  if (l==0) auxl[c]=aw;
  sl[c][l]=sp;
  const float* wgn = Wgain + c*DC*DC;
  float gn=0.f;
#pragma unroll
  for (int d=0; d<DC; ++d) gn = fmaf(sl[c][d], wgn[d*DC+l], gn);
  float hg = hv*(1.f+tanhf(gn));
  H[idx]=hg; TS[idx]=tanhf(sp);
  hl[c][l]=hg;
  const float* wsw = Wsw + c*DC*2*DC;
  float s0=bsw[c*2*DC+l], s1=bsw[c*2*DC+64+l];
#pragma unroll
  for (int d=0; d<DC; ++d){ float hd=hl[c][d]; s0=fmaf(hd,wsw[d*2*DC+l],s0); s1=fmaf(hd,wsw[d*2*DC+64+l],s1); }
  SEED[idx]=s0; WC[idx]=s1;
  float wq = wsum(s1*s1);
  if (l==0) wcl[c]=wq;
  __syncthreads();
  if (threadIdx.x==0){
    float a=0.f, wn=0.f;
    for(int i=0;i<NC;++i){ a+=auxl[i]; wn+=wcl[i]; }
    auxp[bn]=a; WCN[bn]=sqrtf(wn);
  }
}

// ================= slot norms =================
__global__ __launch_bounds__(64) void k_snorm(const float* __restrict__ slots, float* __restrict__ snorm){
  int r = blockIdx.x; int l=threadIdx.x;
  const float* s = slots + (size_t)r*DIM;
  float acc=0.f;
#pragma unroll
  for (int j=0;j<8;++j){ float v=s[j*64+l]; acc=fmaf(v,v,acc); }
  acc = wsum(acc);
  if (l==0) snorm[r]=sqrtf(acc);
}

// ================= G = slots @ slotsT per (b,k): [64,64], K=512 ============
__global__ __launch_bounds__(256) void k_emg(const float* __restrict__ slots, float* __restrict__ G){
  __shared__ float As[16][68];
  int bk = blockIdx.x;
  const float* S = slots + (size_t)bk*NSLOT*DIM;
  int t = threadIdx.x;
  int rowg = t>>4, colg = t&15;
  float acc[4][4];
#pragma unroll
  for (int i=0;i<4;++i)
#pragma unroll
    for (int j=0;j<4;++j) acc[i][j]=0.f;
  for (int k0=0;k0<DIM;k0+=16){
    int r = t>>2, kq = (t&3)*4;
    float4 f = *(const float4*)&S[(size_t)r*DIM + k0 + kq];
    As[kq][r]=f.x; As[kq+1][r]=f.y; As[kq+2][r]=f.z; As[kq+3][r]=f.w;
    __syncthreads();
#pragma unroll
    for (int kk=0;kk<16;++kk){
      float av[4], bv[4];
#pragma unroll
      for (int i=0;i<4;++i) av[i]=As[kk][rowg*4+i];
#pragma unroll
      for (int j=0;j<4;++j) bv[j]=As[kk][colg+16*j];
#pragma unroll
      for (int i=0;i<4;++i)
#pragma unroll
        for (int j=0;j<4;++j) acc[i][j]=fmaf(av[i],bv[j],acc[i][j]);
    }
    __syncthreads();
  }
  float* g = G + (size_t)bk*NSLOT*NSLOT;
#pragma unroll
  for (int i=0;i<4;++i)
#pragma unroll
    for (int j=0;j<4;++j) g[(size_t)(rowg*4+i)*NSLOT + colg+16*j] = acc[i][j];
}

// ====== shared GEMM-tile pattern: 128 rows x 64 cols (one bank), K=512 ======
// epilogue EP: 0 = softmax -> ATT1 ; 1 = normalized max -> MX (k_sim)
template<int EP>
__global__ __launch_bounds__(256) void k_score(const float* __restrict__ A,
    const float* __restrict__ slots, const float* __restrict__ WCN,
    const float* __restrict__ SNORM, float* __restrict__ OUT){
  __shared__ float As[16][132];
  __shared__ float Bs[16][68];
  __shared__ float sc[128][68];
  int k = blockIdx.x, row0 = blockIdx.y*128, b = blockIdx.z;
  int t = threadIdx.x;
  int rowg = t>>4, colg = t&15;
  const float* Ab = A + ((size_t)b*NSEQ + row0)*DIM;
  const float* Sb = slots + ((size_t)(b*NBANK+k))*NSLOT*DIM;
  float acc[8][4];
#pragma unroll
  for (int i=0;i<8;++i)
#pragma unroll
    for (int j=0;j<4;++j) acc[i][j]=0.f;
  for (int k0=0;k0<DIM;k0+=16){
#pragma unroll
    for (int e=0;e<2;++e){
      int u=t+256*e; int r=u>>2, kq=(u&3)*4;
      float4 f = *(const float4*)&Ab[(size_t)r*DIM + k0+kq];
      As[kq][r]=f.x; As[kq+1][r]=f.y; As[kq+2][r]=f.z; As[kq+3][r]=f.w;
    }
    { int c=t>>2, kq=(t&3)*4;
      float4 f = *(const float4*)&Sb[(size_t)c*DIM + k0+kq];
      Bs[kq][c]=f.x; Bs[kq+1][c]=f.y; Bs[kq+2][c]=f.z; Bs[kq+3][c]=f.w; }
    __syncthreads();
#pragma unroll
    for (int kk=0;kk<16;++kk){
      float av[8], bv[4];
#pragma unroll
      for (int i=0;i<8;++i) av[i]=As[kk][rowg*8+i];
#pragma unroll
      for (int j=0;j<4;++j) bv[j]=Bs[kk][colg+16*j];
#pragma unroll
      for (int i=0;i<8;++i)
#pragma unroll
        for (int j=0;j<4;++j) acc[i][j]=fmaf(av[i],bv[j],acc[i][j]);
    }
    __syncthreads();
  }
#pragma unroll
  for (int i=0;i<8;++i)
#pragma unroll
    for (int j=0;j<4;++j) sc[rowg*8+i][colg+16*j]=acc[i][j];
  __syncthreads();
  if (t<128){
    int row=t;
    if (EP==0){
      const float scale = 0.04419417382415922f;  // 1/sqrt(512)
      float mx=-1e30f;
      for (int c2=0;c2<64;++c2) mx=fmaxf(mx, sc[row][c2]*scale);
      float sm=0.f;
      for (int c2=0;c2<64;++c2) sm+=expf(sc[row][c2]*scale-mx);
      float inv=1.f/sm;
      float* o = OUT + ((size_t)(b*NSEQ)+row0+row)*DIM + k*64;
      for (int c2=0;c2<64;++c2) o[c2]=expf(sc[row][c2]*scale-mx)*inv;
    } else {
      float wcn = WCN[(size_t)b*NSEQ + row0 + row] + 1e-6f;
      const float* nb = SNORM + (size_t)(b*NBANK+k)*NSLOT;
      float mx=-1e30f;
      for (int c2=0;c2<64;++c2) mx=fmaxf(mx, sc[row][c2]/(wcn*(nb[c2]+1e-6f)));
      OUT[((size_t)(b*NSEQ)+row0+row)*NBANK + k] = mx;
    }
  }
}

// ====== scores2 = att1[b,:,k,:] @ G[b,k] (K=64), softmax -> ATT2 ============
__global__ __launch_bounds__(256) void k_emscore2(const float* __restrict__ ATT1,
    const float* __restrict__ G, float* __restrict__ ATT2){
  __shared__ float As[64][132];
  __shared__ float Gs[64][68];
  __shared__ float sc[128][68];
  int k = blockIdx.x, row0 = blockIdx.y*128, b = blockIdx.z;
  int t = threadIdx.x;
  int rowg = t>>4, colg = t&15;
#pragma unroll
  for (int e=0;e<8;++e){
    int idx=t+256*e; int row=idx>>4, kq=(idx&15)*4;
    float4 f = *(const float4*)&ATT1[((size_t)(b*NSEQ)+row0+row)*DIM + k*64 + kq];
    As[kq][row]=f.x; As[kq+1][row]=f.y; As[kq+2][row]=f.z; As[kq+3][row]=f.w;
  }
#pragma unroll
  for (int e=0;e<4;++e){
    int idx=t+256*e; int m=idx>>4, c4=(idx&15)*4;
    float4 f = *(const float4*)&G[((size_t)(b*NBANK+k)*NSLOT + m)*NSLOT + c4];
    *(float4*)&Gs[m][c4] = f;
  }
  __syncthreads();
  float acc[8][4];
#pragma unroll
  for (int i=0;i<8;++i)
#pragma unroll
    for (int j=0;j<4;++j) acc[i][j]=0.f;
#pragma unroll 4
  for (int m=0;m<64;++m){
    float av[8], bv[4];
#pragma unroll
    for (int i=0;i<8;++i) av[i]=As[m][rowg*8+i];
#pragma unroll
    for (int j=0;j<4;++j) bv[j]=Gs[m][colg+16*j];
#pragma unroll
    for (int i=0;i<8;++i)
#pragma unroll
      for (int j=0;j<4;++j) acc[i][j]=fmaf(av[i],bv[j],acc[i][j]);
  }
#pragma unroll
  for (int i=0;i<8;++i)
#pragma unroll
    for (int j=0;j<4;++j) sc[rowg*8+i][colg+16*j]=acc[i][j];
  __syncthreads();
  if (t<128){
    int row=t;
    const float scale = 0.04419417382415922f;
    float mx=-1e30f;
    for (int c2=0;c2<64;++c2) mx=fmaxf(mx, sc[row][c2]*scale);
    float sm=0.f;
    for (int c2=0;c2<64;++c2) sm+=expf(sc[row][c2]*scale-mx);
    float inv=1.f/sm;
    float* o = ATT2 + (((size_t)(b*NSEQ)+row0+row)*NBANK + k)*NSLOT;
    for (int c2=0;c2<64;++c2) o[c2]=expf(sc[row][c2]*scale-mx)*inv;
  }
}

// ====== PV2: INTEG[b] += ATT2[b] ([512 x 512km]) @ slots[b] ([512km x 512]) =
__global__ __launch_bounds__(256) void k_empv2(const float* __restrict__ ATT2,
    const float* __restrict__ slots, float* __restrict__ INTEG){
  __shared__ float As[16][132];
  __shared__ float Bs[16][68];
  int col0 = blockIdx.x*64, row0 = blockIdx.y*128, b = blockIdx.z;
  int t = threadIdx.x;
  int rowg = t>>4, colg = t&15;
  const float* Ab = ATT2 + ((size_t)b*NSEQ + row0)*DIM;
  const float* Sb = slots + (size_t)b*NBANK*NSLOT*DIM;
  float acc[8][4];
#pragma unroll
  for (int i=0;i<8;++i)
#pragma unroll
    for (int j=0;j<4;++j) acc[i][j]=0.f;
  for (int k0=0;k0<DIM;k0+=16){
#pragma unroll
    for (int e=0;e<2;++e){
      int u=t+256*e; int r=u>>2, kq=(u&3)*4;
      float4 f = *(const float4*)&Ab[(size_t)r*DIM + k0+kq];
      As[kq][r]=f.x; As[kq+1][r]=f.y; As[kq+2][r]=f.z; As[kq+3][r]=f.w;
    }
    { int kq=t>>4, c4=(t&15)*4;
      float4 f = *(const float4*)&Sb[(size_t)(k0+kq)*DIM + col0 + c4];
      *(float4*)&Bs[kq][c4] = f; }
    __syncthreads();
#pragma unroll
    for (int kk=0;kk<16;++kk){
      float av[8], bv[4];
#pragma unroll
      for (int i=0;i<8;++i) av[i]=As[kk][rowg*8+i];
#pragma unroll
      for (int j=0;j<4;++j) bv[j]=Bs[kk][colg+16*j];
#pragma unroll
      for (int i=0;i<8;++i)
#pragma unroll
        for (int j=0;j<4;++j) acc[i][j]=fmaf(av[i],bv[j],acc[i][j]);
    }
    __syncthreads();
  }
#pragma unroll
  for (int i=0;i<8;++i)
#pragma unroll
    for (int j=0;j<4;++j){
      size_t o = ((size_t)(b*NSEQ)+row0+rowg*8+i)*DIM + col0 + colg+16*j;
      INTEG[o] += acc[i][j];
    }
}

// ====== gates/novelty per row (1 wave per row) =============================
__global__ __launch_bounds__(64) void k_gates(const float* __restrict__ H,
    const float* __restrict__ wnovW, const float* __restrict__ wnovb,
    const float* __restrict__ WkeyW, const float* __restrict__ MX,
    float* __restrict__ GATE, float* __restrict__ NSUM){
  int bn = blockIdx.x; int l = threadIdx.x;
  const float* hrow = H + (size_t)bn*DIM;
  float pn[8], pg[8];
#pragma unroll
  for (int k=0;k<8;++k){ pn[k]=0.f; pg[k]=0.f; }
#pragma unroll
  for (int j=0;j<8;++j){
    int d=j*64+l; float hv=hrow[d];
#pragma unroll
    for (int k=0;k<8;++k){ pn[k]=fmaf(hv,wnovW[d*NBANK+k],pn[k]); pg[k]=fmaf(hv,WkeyW[d*NBANK+k],pg[k]); }
  }
  float nsum=0.f;
#pragma unroll
  for (int k=0;k<8;++k){
    float sn = wsum(pn[k]);
    float sg = wsum(pg[k]);
    float wn = sigm(sn + wnovb[k]);
    float nv = wn * fminf(fmaxf(1.f - MX[(size_t)bn*NBANK+k],0.f),1.f);
    nsum += nv;
    if (l==0) GATE[(size_t)bn*NBANK+k]=sigm(sg);
  }
  if (l==0) NSUM[bn]=nsum;
}

// ====== causal cumsums ======================================================
__global__ __launch_bounds__(512) void k_cum(const float* __restrict__ TS, const float* __restrict__ WC,
    const float* __restrict__ NSUM, const float* __restrict__ H,
    float* __restrict__ CUMTS, float* __restrict__ INTEG){
  int b=blockIdx.x; int d=threadIdx.x;
  float ats=0.f, acw=0.f;
  for (int n=0;n<NSEQ;++n){
    size_t i=((size_t)b*NSEQ+n)*DIM+d;
    ats += TS[i]; CUMTS[i]=ats;
    acw = fmaf(NSUM[b*NSEQ+n], WC[i], acw);
    INTEG[i] = H[i] + acw;
  }
}

// ====== PM: INTEG += sum_k gate*tanh(pm_state + eta*cumts@Ww_k) =============
#define TNR 16
__global__ __launch_bounds__(256) void k_pm(const float* __restrict__ CUMTS, const float* __restrict__ GATE,
    const float* __restrict__ pmstate, const float* __restrict__ Wwrite, float* __restrict__ INTEG){
  int f  = blockIdx.x*256 + threadIdx.x;
  int r0 = blockIdx.y*TNR;
  int b  = r0>>9;
  const float* ts0 = CUMTS + (size_t)r0*DIM;
  float out[TNR];
#pragma unroll
  for (int t=0;t<TNR;++t) out[t]=0.f;
  for (int k=0;k<NBANK;++k){
    float acc[TNR];
#pragma unroll
    for (int t=0;t<TNR;++t) acc[t]=0.f;
    const float* wk = Wwrite + (size_t)k*DIM*DIM + f;
    for (int d=0; d<DIM; ++d){
      float wv = wk[(size_t)d*DIM];
#pragma unroll
      for (int t=0;t<TNR;++t) acc[t] = fmaf(ts0[(size_t)t*DIM + d], wv, acc[t]);
    }
    float ps = pmstate[((size_t)b*NBANK+k)*DIM + f];
#pragma unroll
    for (int t=0;t<TNR;++t){
      float g = GATE[(size_t)(r0+t)*NBANK + k];
      out[t] = fmaf(g, tanhf(fmaf(ETA_PM, acc[t], ps)), out[t]);
    }
  }
#pragma unroll
  for (int t=0;t<TNR;++t){ size_t i=((size_t)(r0+t))*DIM+f; INTEG[i] += out[t]; }
}

// ================= final LN =================
__global__ __launch_bounds__(512) void k_lnf(const float* __restrict__ Hp,
    const float* __restrict__ g, const float* __restrict__ bb, float* __restrict__ O){
  __shared__ float red[NC];
  int bn=blockIdx.x; int w=threadIdx.x>>6, l=threadIdx.x&63; int d=threadIdx.x;
  float x = Hp[(size_t)bn*DIM+d];
  float s = wsum(x);
  if (l==0) red[w]=s;
  __syncthreads();
  float tot=0.f; for(int i=0;i<NC;++i) tot+=red[i];
  float mu = tot*(1.f/512.f);
  float dv = x-mu;
  float vs = wsum(dv*dv);
  __syncthreads();
  if (l==0) red[w]=vs;
  __syncthreads();
  float vt=0.f; for(int i=0;i<NC;++i) vt+=red[i];
  O[(size_t)bn*DIM+d] = dv*rsqrtf(vt*(1.f/512.f)+1e-5f)*g[d]+bb[d];
}

// ====== logits GEMM: C[2048,32000] = A[2048,512] @ emb^T (strided cols) =====
__global__ __launch_bounds__(256) void k_gemm(const float* __restrict__ A, const float* __restrict__ Bm,
    float* __restrict__ Cm){
  __shared__ float As[16][132];
  __shared__ float Bs[16][132];
  const int tid = threadIdx.x;
  const int colg = tid & 15;
  const int rowg = tid >> 4;
  const int row0 = blockIdx.y*128;
  const int col0 = blockIdx.x*128;
  float acc[8][8];
#pragma unroll
  for (int i=0;i<8;++i)
#pragma unroll
    for (int j=0;j<8;++j) acc[i][j]=0.f;
  for (int k0=0;k0<DIM;k0+=16){
#pragma unroll
    for (int i=0;i<2;++i){
      int u = tid + 256*i;
      int r = u >> 2;
      int kq = (u & 3)*4;
      float4 a4 = *(const float4*)&A [(size_t)(row0+r)*DIM + k0 + kq];
      As[kq  ][r]=a4.x; As[kq+1][r]=a4.y; As[kq+2][r]=a4.z; As[kq+3][r]=a4.w;
      float4 b4 = *(const float4*)&Bm[(size_t)(col0+r)*DIM + k0 + kq];
      Bs[kq  ][r]=b4.x; Bs[kq+1][r]=b4.y; Bs[kq+2][r]=b4.z; Bs[kq+3][r]=b4.w;
    }
    __syncthreads();
#pragma unroll
    for (int k=0;k<16;++k){
      float av[8], bv[8];
#pragma unroll
      for (int i=0;i<8;++i) av[i]=As[k][rowg*8+i];
#pragma unroll
      for (int j=0;j<8;++j) bv[j]=Bs[k][colg+16*j];   // strided: conflict-free
#pragma unroll
      for (int i=0;i<8;++i)
#pragma unroll
        for (int j=0;j<8;++j) acc[i][j] = fmaf(av[i], bv[j], acc[i][j]);
    }
    __syncthreads();
  }
#pragma unroll
  for (int i=0;i<8;++i){
    size_t rb = (size_t)(row0+rowg*8+i)*VOC + col0;
#pragma unroll
    for (int j=0;j<8;++j) Cm[rb + colg + 16*j] = acc[i][j];
  }
}

// ================= aux loss =================
__global__ __launch_bounds__(256) void k_aux(const float* __restrict__ auxp, float* __restrict__ out){
  __shared__ float red[4];
  float s=0.f;
  for (int i=threadIdx.x;i<NROW;i+=256) s+=auxp[i];
  s = wsum(s);
  int w=threadIdx.x>>6, l=threadIdx.x&63;
  if (l==0) red[w]=s;
  __syncthreads();
  if (threadIdx.x==0){
    float t=red[0]+red[1]+red[2]+red[3];
    out[(size_t)NROW*VOC] = PCM_W * t / (float)(NROW*NC*DC);
  }
}

// ================= host launch =================
extern "C" void kernel_launch(void* const* d_in, const int* in_sizes, int n_in,
                              void* d_out, int out_size, void* d_ws, size_t ws_size,
                              hipStream_t stream){
  const int*   ids    = (const int*)  d_in[0];
  const float* emb    = (const float*)d_in[1];
  const float* pos    = (const float*)d_in[2];
  const float* s1Wv   = (const float*)d_in[3];
  const float* s1Wg   = (const float*)d_in[4];
  const float* s1al   = (const float*)d_in[5];
  const float* s1W1   = (const float*)d_in[6];
  const float* s1W2   = (const float*)d_in[7];
  const float* s1lng  = (const float*)d_in[8];
  const float* s1lnb  = (const float*)d_in[9];
  const float* s3Wv   = (const float*)d_in[10];
  const float* s3Wg   = (const float*)d_in[11];
  const float* s3al   = (const float*)d_in[12];
  const float* s3W1   = (const float*)d_in[13];
  const float* s3W2   = (const float*)d_in[14];
  const float* s3lng  = (const float*)d_in[15];
  const float* s3lnb  = (const float*)d_in[16];
  const float* seedwW = (const float*)d_in[17];
  const float* seedwb = (const float*)d_in[18];
  const float* Wpred  = (const float*)d_in[19];
  const float* bpred  = (const float*)d_in[20];
  const float* Wgain  = (const float*)d_in[21];
  const float* wnovW  = (const float*)d_in[22];
  const float* wnovb  = (const float*)d_in[23];
  const float* Wwrite = (const float*)d_in[24];
  const float* WkeyW  = (const float*)d_in[25];
  const float* pmst   = (const float*)d_in[26];
  const float* slots  = (const float*)d_in[27];
  const float* lnfg   = (const float*)d_in[28];
  const float* lnfb   = (const float*)d_in[29];

  float* ws = (float*)d_ws;
  const size_t U = 1u<<20;        // 1M floats
  float* X     = ws + 0*U;   // aliased: ATT1 (X dead after k_pcm)
  float* H     = ws + 1*U;
  float* Vb    = ws + 2*U;
  float* Gb    = ws + 3*U;
  float* TS    = ws + 4*U;   // aliased: ATT2 (TS dead after k_cum)
  float* SEED  = ws + 5*U;
  float* WC    = ws + 6*U;
  float* CUMTS = ws + 7*U;
  float* INTEG = ws + 8*U;
  float* LNOUT = ws + 9*U;
  float* ATT1  = X;
  float* ATT2  = TS;
  float* tail  = ws + 10*U;
  float* SNORM = tail;                    // 2048
  float* GATE  = SNORM + 2048;            // 16384
  float* NSUM  = GATE + NROW*NBANK;       // 2048
  float* AUXP  = NSUM + NROW;             // 2048
  float* MXB   = AUXP + NROW;             // 16384
  float* WCN   = MXB + NROW*NBANK;        // 2048
  float* GBUF  = WCN + NROW;              // 131072

  float* logits = (float*)d_out;

  k_embed <<<NROW,256,0,stream>>>(ids,emb,pos,X,H);
  k_snorm <<<BSZ*NBANK*NSLOT,64,0,stream>>>(slots,SNORM);
  k_emg   <<<BSZ*NBANK,256,0,stream>>>(slots,GBUF);

  for (int i=0;i<2;++i){
    k_lnvg<<<NC*(NROW/8),512,0,stream>>>(H, s1Wv+i*NC*DC*DC, s1Wg+i*NC*DC*DC,
                                          s1lng+i*DC, s1lnb+i*DC, Vb, Gb);
    k_scan<<<BSZ*NC,512,0,stream>>>(Vb, s1al+i*NC*DC);
    k_mlp <<<NC*(NROW/8),512,0,stream>>>(H, Vb, Gb, s1W1+i*NC*DC*EDIM, s1W2+i*NC*EDIM*DC);
  }

  k_pcm     <<<NROW,512,0,stream>>>(X,H,Wpred,bpred,Wgain,seedwW,seedwb,TS,SEED,WC,WCN,AUXP);
  k_score<1><<<dim3(NBANK,4,BSZ),256,0,stream>>>(WC,  slots,WCN,SNORM,MXB);
  k_gates   <<<NROW,64,0,stream>>>(H,wnovW,wnovb,WkeyW,MXB,GATE,NSUM);
  k_cum     <<<BSZ,512,0,stream>>>(TS,WC,NSUM,H,CUMTS,INTEG);
  k_pm      <<<dim3(2,NROW/TNR),256,0,stream>>>(CUMTS,GATE,pmst,Wwrite,INTEG);
  k_score<0><<<dim3(NBANK,4,BSZ),256,0,stream>>>(SEED,slots,WCN,SNORM,ATT1);
  k_emscore2<<<dim3(NBANK,4,BSZ),256,0,stream>>>(ATT1,GBUF,ATT2);
  k_empv2   <<<dim3(8,4,BSZ),256,0,stream>>>(ATT2,slots,INTEG);

  for (int i=0;i<2;++i){
    k_lnvg<<<NC*(NROW/8),512,0,stream>>>(INTEG, s3Wv+i*NC*DC*DC, s3Wg+i*NC*DC*DC,
                                          s3lng+i*DC, s3lnb+i*DC, Vb, Gb);
    k_scan<<<BSZ*NC,512,0,stream>>>(Vb, s3al+i*NC*DC);
    k_mlp <<<NC*(NROW/8),512,0,stream>>>(INTEG, Vb, Gb, s3W1+i*NC*DC*EDIM, s3W2+i*NC*EDIM*DC);
  }

  k_lnf <<<NROW,512,0,stream>>>(INTEG,lnfg,lnfb,LNOUT);
  k_gemm<<<dim3(VOC/128, NROW/128),256,0,stream>>>(LNOUT,emb,logits);
  k_aux <<<1,256,0,stream>>>(AUXP,logits);
}

// Round 3
// 1832.452 us; speedup vs baseline: 1.4307x; 1.4307x over previous
//
#include <hip/hip_runtime.h>
#include <math.h>

// ---- problem constants ----
#define BSZ   4
#define NSEQ  512
#define NC    8       // C channels
#define DC    64      // per-column dim
#define DIM   512     // D = C*DC
#define EDIM  128     // MLP hidden
#define NBANK 8       // B
#define NSLOT 64      // M
#define VOC   32000
#define NROW  (BSZ*NSEQ)   // 2048
#define ETA_PM 0.1f
#define PCM_W  0.1f

// ---- helpers ----
__device__ __forceinline__ float wsum(float v){
#pragma unroll
  for (int m=1;m<64;m<<=1) v += __shfl_xor(v,m,64);
  return v;
}
__device__ __forceinline__ float sigm(float x){ return 1.f/(1.f+expf(-x)); }
__device__ __forceinline__ float gelu_f(float x){
  float x3 = x*x*x;
  return 0.5f*x*(1.f+tanhf(0.7978845608028654f*(x+0.044715f*x3)));
}

// ================= embed =================
__global__ __launch_bounds__(256) void k_embed(const int* __restrict__ ids,
    const float* __restrict__ emb, const float* __restrict__ pos,
    float* __restrict__ X, float* __restrict__ H){
  int bn = blockIdx.x;               // b*NSEQ+n
  int n  = bn & (NSEQ-1);
  int id = ids[bn];
  const float* e = emb + (size_t)id*DIM;
  const float* p = pos + (size_t)n*DIM;
  float* x = X + (size_t)bn*DIM;
  float* h = H + (size_t)bn*DIM;
  for (int d=threadIdx.x; d<DIM; d+=256){ float v = e[d]+p[d]; x[d]=v; h[d]=v; }
}

// ================= scan layer: LN + v,g =================
__global__ __launch_bounds__(512) void k_lnvg(const float* __restrict__ H,
    const float* __restrict__ Wv, const float* __restrict__ Wg,
    const float* __restrict__ lng, const float* __restrict__ lnb,
    float* __restrict__ Vb, float* __restrict__ Gb){
  __shared__ float wv[DC*DC];
  __shared__ float wg[DC*DC];
  __shared__ float hl[8][DC];
  int c    = blockIdx.x & 7;
  int tile = blockIdx.x >> 3;
  int w = threadIdx.x>>6, l = threadIdx.x&63;
  for (int i=threadIdx.x; i<DC*DC; i+=512){ wv[i]=Wv[c*DC*DC+i]; wg[i]=Wg[c*DC*DC+i]; }
  int bn = tile*8 + w;
  size_t idx = (size_t)bn*DIM + c*DC + l;
  float x = H[idx];
  float mu = wsum(x)*(1.f/64.f);
  float d0 = x-mu;
  float var = wsum(d0*d0)*(1.f/64.f);
  float h = d0*rsqrtf(var+1e-5f)*lng[l] + lnb[l];
  hl[w][l]=h;
  __syncthreads();
  float v=0.f,g=0.f;
#pragma unroll
  for (int d=0; d<DC; ++d){ float hd=hl[w][d]; v = fmaf(hd, wv[d*DC+l], v); g = fmaf(hd, wg[d*DC+l], g); }
  Vb[idx]=v; Gb[idx]=sigm(g);
}

// ================= gated linear scan, chunked 2-pass (block = one (b,c)) ====
__global__ __launch_bounds__(512) void k_scan(float* __restrict__ Vb, const float* __restrict__ alog){
  __shared__ float VW[8][64];
  int b = blockIdx.x>>3, c = blockIdx.x&7;
  int w = threadIdx.x>>6, e = threadIdx.x&63;
  float a = sigm(alog[c*DC+e]);
  float a2=a*a, a4=a2*a2, a8=a4*a4, a16=a8*a8, a32=a16*a16, a64=a32*a32;
  size_t base = ((size_t)(b*NSEQ + w*64)*NC + c)*DC + e;   // n = w*64+i, step 512 floats
  float s=0.f;
#pragma unroll 8
  for (int i=0;i<64;++i) s = fmaf(a, s, Vb[base + (size_t)i*512]);
  VW[w][e]=s;
  __syncthreads();
  float carry=0.f;
  for (int wp=0; wp<w; ++wp) carry = fmaf(carry, a64, VW[wp][e]);  // wave-uniform trip count
  s = carry;
#pragma unroll 8
  for (int i=0;i<64;++i){ size_t ix = base + (size_t)i*512; s = fmaf(a, s, Vb[ix]); Vb[ix]=s; }
}

// ================= scan layer: u=g*S, MLP, residual =================
__global__ __launch_bounds__(512) void k_mlp(float* __restrict__ H,
    const float* __restrict__ Sb, const float* __restrict__ Gb,
    const float* __restrict__ W1, const float* __restrict__ W2){
  __shared__ float w1[DC*EDIM];
  __shared__ float w2[EDIM*DC];
  __shared__ float ul[8][DC];
  __shared__ float tl[8][EDIM];
  int c    = blockIdx.x & 7;
  int tile = blockIdx.x >> 3;
  int w = threadIdx.x>>6, l = threadIdx.x&63;
  for (int i=threadIdx.x; i<DC*EDIM; i+=512){ w1[i]=W1[c*DC*EDIM+i]; w2[i]=W2[c*EDIM*DC+i]; }
  int bn = tile*8 + w;
  size_t idx = (size_t)bn*DIM + c*DC + l;
  float u = Sb[idx]*Gb[idx];
  ul[w][l]=u;
  __syncthreads();
  float t0=0.f,t1=0.f;
#pragma unroll
  for (int d=0; d<DC; ++d){ float ud=ul[w][d]; t0 = fmaf(ud, w1[d*EDIM+l], t0); t1 = fmaf(ud, w1[d*EDIM+64+l], t1); }
  tl[w][l]=gelu_f(t0); tl[w][64+l]=gelu_f(t1);
  float y=0.f;
#pragma unroll
  for (int e2=0; e2<EDIM; ++e2) y = fmaf(tl[w][e2], w2[e2*DC+l], y);
  H[idx] += y;
}

// ================= PCM + seed/w_cand heads (+ wc norm) =================
__global__ __launch_bounds__(512) void k_pcm(const float* __restrict__ X, float* __restrict__ H,
    const float* __restrict__ Wpred, const float* __restrict__ bpred, const float* __restrict__ Wgain,
    const float* __restrict__ Wsw, const float* __restrict__ bsw,
    float* __restrict__ TS, float* __restrict__ SEED, float* __restrict__ WC,
    float* __restrict__ WCN, float* __restrict__ auxp){
  __shared__ float hl[NC][DC];
  __shared__ float sl[NC][DC];
  __shared__ float auxl[NC];
  __shared__ float wcl[NC];
  int bn=blockIdx.x; int c=threadIdx.x>>6; int l=threadIdx.x&63;
  size_t idx=(size_t)bn*DIM + c*DC + l;
  float hv=H[idx], xv=X[idx];
  hl[c][l]=hv;
  const float* wp = Wpred + c*DC*DC;
  float z = bpred[c*DC+l];
#pragma unroll
  for (int d=0; d<DC; ++d) z = fmaf(hl[c][d], wp[d*DC+l], z);
  float sp = xv - z;
  float aw = wsum(sp*sp);
  if (l==0) auxl[c]=aw;
  sl[c][l]=sp;
  const float* wgn = Wgain + c*DC*DC;
  float gn=0.f;
#pragma unroll
  for (int d=0; d<DC; ++d) gn = fmaf(sl[c][d], wgn[d*DC+l], gn);
  float hg = hv*(1.f+tanhf(gn));
  H[idx]=hg; TS[idx]=tanhf(sp);
  hl[c][l]=hg;
  const float* wsw = Wsw + c*DC*2*DC;
  float s0=bsw[c*2*DC+l], s1=bsw[c*2*DC+64+l];
#pragma unroll
  for (int d=0; d<DC; ++d){ float hd=hl[c][d]; s0=fmaf(hd,wsw[d*2*DC+l],s0); s1=fmaf(hd,wsw[d*2*DC+64+l],s1); }
  SEED[idx]=s0; WC[idx]=s1;
  float wq = wsum(s1*s1);
  if (l==0) wcl[c]=wq;
  __syncthreads();
  if (threadIdx.x==0){
    float a=0.f, wn=0.f;
    for(int i=0;i<NC;++i){ a+=auxl[i]; wn+=wcl[i]; }
    auxp[bn]=a; WCN[bn]=sqrtf(wn);
  }
}

// ================= slot norms =================
__global__ __launch_bounds__(64) void k_snorm(const float* __restrict__ slots, float* __restrict__ snorm){
  int r = blockIdx.x; int l=threadIdx.x;
  const float* s = slots + (size_t)r*DIM;
  float acc=0.f;
#pragma unroll
  for (int j=0;j<8;++j){ float v=s[j*64+l]; acc=fmaf(v,v,acc); }
  acc = wsum(acc);
  if (l==0) snorm[r]=sqrtf(acc);
}

// ================= G = slots @ slotsT per (b,k): [64,64], K=512 ============
__global__ __launch_bounds__(256) void k_emg(const float* __restrict__ slots, float* __restrict__ G){
  __shared__ float As[16][68];
  int bk = blockIdx.x;
  const float* S = slots + (size_t)bk*NSLOT*DIM;
  int t = threadIdx.x;
  int rowg = t>>4, colg = t&15;
  float acc[4][4];
#pragma unroll
  for (int i=0;i<4;++i)
#pragma unroll
    for (int j=0;j<4;++j) acc[i][j]=0.f;
  for (int k0=0;k0<DIM;k0+=16){
    int r = t>>2, kq = (t&3)*4;
    float4 f = *(const float4*)&S[(size_t)r*DIM + k0 + kq];
    As[kq][r]=f.x; As[kq+1][r]=f.y; As[kq+2][r]=f.z; As[kq+3][r]=f.w;
    __syncthreads();
#pragma unroll
    for (int kk=0;kk<16;++kk){
      float av[4], bv[4];
#pragma unroll
      for (int i=0;i<4;++i) av[i]=As[kk][rowg*4+i];
#pragma unroll
      for (int j=0;j<4;++j) bv[j]=As[kk][colg+16*j];
#pragma unroll
      for (int i=0;i<4;++i)
#pragma unroll
        for (int j=0;j<4;++j) acc[i][j]=fmaf(av[i],bv[j],acc[i][j]);
    }
    __syncthreads();
  }
  float* g = G + (size_t)bk*NSLOT*NSLOT;
#pragma unroll
  for (int i=0;i<4;++i)
#pragma unroll
    for (int j=0;j<4;++j) g[(size_t)(rowg*4+i)*NSLOT + colg+16*j] = acc[i][j];
}

// ====== shared GEMM-tile pattern: 128 rows x 64 cols (one bank), K=512 ======
// epilogue EP: 0 = softmax -> ATT1 ; 1 = normalized max -> MX (k_sim)
template<int EP>
__global__ __launch_bounds__(256) void k_score(const float* __restrict__ A,
    const float* __restrict__ slots, const float* __restrict__ WCN,
    const float* __restrict__ SNORM, float* __restrict__ OUT){
  __shared__ float As[16][132];
  __shared__ float Bs[16][68];
  __shared__ float sc[128][68];
  int k = blockIdx.x, row0 = blockIdx.y*128, b = blockIdx.z;
  int t = threadIdx.x;
  int rowg = t>>4, colg = t&15;
  const float* Ab = A + ((size_t)b*NSEQ + row0)*DIM;
  const float* Sb = slots + ((size_t)(b*NBANK+k))*NSLOT*DIM;
  float acc[8][4];
#pragma unroll
  for (int i=0;i<8;++i)
#pragma unroll
    for (int j=0;j<4;++j) acc[i][j]=0.f;
  for (int k0=0;k0<DIM;k0+=16){
#pragma unroll
    for (int e=0;e<2;++e){
      int u=t+256*e; int r=u>>2, kq=(u&3)*4;
      float4 f = *(const float4*)&Ab[(size_t)r*DIM + k0+kq];
      As[kq][r]=f.x; As[kq+1][r]=f.y; As[kq+2][r]=f.z; As[kq+3][r]=f.w;
    }
    { int c=t>>2, kq=(t&3)*4;
      float4 f = *(const float4*)&Sb[(size_t)c*DIM + k0+kq];
      Bs[kq][c]=f.x; Bs[kq+1][c]=f.y; Bs[kq+2][c]=f.z; Bs[kq+3][c]=f.w; }
    __syncthreads();
#pragma unroll
    for (int kk=0;kk<16;++kk){
      float av[8], bv[4];
#pragma unroll
      for (int i=0;i<8;++i) av[i]=As[kk][rowg*8+i];
#pragma unroll
      for (int j=0;j<4;++j) bv[j]=Bs[kk][colg+16*j];
#pragma unroll
      for (int i=0;i<8;++i)
#pragma unroll
        for (int j=0;j<4;++j) acc[i][j]=fmaf(av[i],bv[j],acc[i][j]);
    }
    __syncthreads();
  }
#pragma unroll
  for (int i=0;i<8;++i)
#pragma unroll
    for (int j=0;j<4;++j) sc[rowg*8+i][colg+16*j]=acc[i][j];
  __syncthreads();
  if (t<128){
    int row=t;
    if (EP==0){
      const float scale = 0.04419417382415922f;  // 1/sqrt(512)
      float mx=-1e30f;
      for (int c2=0;c2<64;++c2) mx=fmaxf(mx, sc[row][c2]*scale);
      float sm=0.f;
      for (int c2=0;c2<64;++c2) sm+=expf(sc[row][c2]*scale-mx);
      float inv=1.f/sm;
      float* o = OUT + ((size_t)(b*NSEQ)+row0+row)*DIM + k*64;
      for (int c2=0;c2<64;++c2) o[c2]=expf(sc[row][c2]*scale-mx)*inv;
    } else {
      float wcn = WCN[(size_t)b*NSEQ + row0 + row] + 1e-6f;
      const float* nb = SNORM + (size_t)(b*NBANK+k)*NSLOT;
      float mx=-1e30f;
      for (int c2=0;c2<64;++c2) mx=fmaxf(mx, sc[row][c2]/(wcn*(nb[c2]+1e-6f)));
      OUT[((size_t)(b*NSEQ)+row0+row)*NBANK + k] = mx;
    }
  }
}

// ====== scores2 = att1[b,:,k,:] @ G[b,k] (K=64), softmax -> ATT2 ============
__global__ __launch_bounds__(256) void k_emscore2(const float* __restrict__ ATT1,
    const float* __restrict__ G, float* __restrict__ ATT2){
  __shared__ float As[64][132];
  __shared__ float Gs[64][68];
  __shared__ float sc[128][68];
  int k = blockIdx.x, row0 = blockIdx.y*128, b = blockIdx.z;
  int t = threadIdx.x;
  int rowg = t>>4, colg = t&15;
#pragma unroll
  for (int e=0;e<8;++e){
    int idx=t+256*e; int row=idx>>4, kq=(idx&15)*4;
    float4 f = *(const float4*)&ATT1[((size_t)(b*NSEQ)+row0+row)*DIM + k*64 + kq];
    As[kq][row]=f.x; As[kq+1][row]=f.y; As[kq+2][row]=f.z; As[kq+3][row]=f.w;
  }
#pragma unroll
  for (int e=0;e<4;++e){
    int idx=t+256*e; int m=idx>>4, c4=(idx&15)*4;
    float4 f = *(const float4*)&G[((size_t)(b*NBANK+k)*NSLOT + m)*NSLOT + c4];
    *(float4*)&Gs[m][c4] = f;
  }
  __syncthreads();
  float acc[8][4];
#pragma unroll
  for (int i=0;i<8;++i)
#pragma unroll
    for (int j=0;j<4;++j) acc[i][j]=0.f;
#pragma unroll 4
  for (int m=0;m<64;++m){
    float av[8], bv[4];
#pragma unroll
    for (int i=0;i<8;++i) av[i]=As[m][rowg*8+i];
#pragma unroll
    for (int j=0;j<4;++j) bv[j]=Gs[m][colg+16*j];
#pragma unroll
    for (int i=0;i<8;++i)
#pragma unroll
      for (int j=0;j<4;++j) acc[i][j]=fmaf(av[i],bv[j],acc[i][j]);
  }
#pragma unroll
  for (int i=0;i<8;++i)
#pragma unroll
    for (int j=0;j<4;++j) sc[rowg*8+i][colg+16*j]=acc[i][j];
  __syncthreads();
  if (t<128){
    int row=t;
    const float scale = 0.04419417382415922f;
    float mx=-1e30f;
    for (int c2=0;c2<64;++c2) mx=fmaxf(mx, sc[row][c2]*scale);
    float sm=0.f;
    for (int c2=0;c2<64;++c2) sm+=expf(sc[row][c2]*scale-mx);
    float inv=1.f/sm;
    float* o = ATT2 + (((size_t)(b*NSEQ)+row0+row)*NBANK + k)*NSLOT;
    for (int c2=0;c2<64;++c2) o[c2]=expf(sc[row][c2]*scale-mx)*inv;
  }
}

// ====== PV2: INTEG[b] += ATT2[b] ([512 x 512km]) @ slots[b] ([512km x 512]) =
__global__ __launch_bounds__(256) void k_empv2(const float* __restrict__ ATT2,
    const float* __restrict__ slots, float* __restrict__ INTEG){
  __shared__ float As[16][132];
  __shared__ float Bs[16][68];
  int col0 = blockIdx.x*64, row0 = blockIdx.y*128, b = blockIdx.z;
  int t = threadIdx.x;
  int rowg = t>>4, colg = t&15;
  const float* Ab = ATT2 + ((size_t)b*NSEQ + row0)*DIM;
  const float* Sb = slots + (size_t)b*NBANK*NSLOT*DIM;
  float acc[8][4];
#pragma unroll
  for (int i=0;i<8;++i)
#pragma unroll
    for (int j=0;j<4;++j) acc[i][j]=0.f;
  for (int k0=0;k0<DIM;k0+=16){
#pragma unroll
    for (int e=0;e<2;++e){
      int u=t+256*e; int r=u>>2, kq=(u&3)*4;
      float4 f = *(const float4*)&Ab[(size_t)r*DIM + k0+kq];
      As[kq][r]=f.x; As[kq+1][r]=f.y; As[kq+2][r]=f.z; As[kq+3][r]=f.w;
    }
    { int kq=t>>4, c4=(t&15)*4;
      float4 f = *(const float4*)&Sb[(size_t)(k0+kq)*DIM + col0 + c4];
      *(float4*)&Bs[kq][c4] = f; }
    __syncthreads();
#pragma unroll
    for (int kk=0;kk<16;++kk){
      float av[8], bv[4];
#pragma unroll
      for (int i=0;i<8;++i) av[i]=As[kk][rowg*8+i];
#pragma unroll
      for (int j=0;j<4;++j) bv[j]=Bs[kk][colg+16*j];
#pragma unroll
      for (int i=0;i<8;++i)
#pragma unroll
        for (int j=0;j<4;++j) acc[i][j]=fmaf(av[i],bv[j],acc[i][j]);
    }
    __syncthreads();
  }
#pragma unroll
  for (int i=0;i<8;++i)
#pragma unroll
    for (int j=0;j<4;++j){
      size_t o = ((size_t)(b*NSEQ)+row0+rowg*8+i)*DIM + col0 + colg+16*j;
      INTEG[o] += acc[i][j];
    }
}

// ====== gates/novelty per row (1 wave per row) =============================
__global__ __launch_bounds__(64) void k_gates(const float* __restrict__ H,
    const float* __restrict__ wnovW, const float* __restrict__ wnovb,
    const float* __restrict__ WkeyW, const float* __restrict__ MX,
    float* __restrict__ GATE, float* __restrict__ NSUM){
  int bn = blockIdx.x; int l = threadIdx.x;
  const float* hrow = H + (size_t)bn*DIM;
  float pn[8], pg[8];
#pragma unroll
  for (int k=0;k<8;++k){ pn[k]=0.f; pg[k]=0.f; }
#pragma unroll
  for (int j=0;j<8;++j){
    int d=j*64+l; float hv=hrow[d];
#pragma unroll
    for (int k=0;k<8;++k){ pn[k]=fmaf(hv,wnovW[d*NBANK+k],pn[k]); pg[k]=fmaf(hv,WkeyW[d*NBANK+k],pg[k]); }
  }
  float nsum=0.f;
#pragma unroll
  for (int k=0;k<8;++k){
    float sn = wsum(pn[k]);
    float sg = wsum(pg[k]);
    float wn = sigm(sn + wnovb[k]);
    float nv = wn * fminf(fmaxf(1.f - MX[(size_t)bn*NBANK+k],0.f),1.f);
    nsum += nv;
    if (l==0) GATE[(size_t)bn*NBANK+k]=sigm(sg);
  }
  if (l==0) NSUM[bn]=nsum;
}

// ====== causal cumsums ======================================================
__global__ __launch_bounds__(512) void k_cum(const float* __restrict__ TS, const float* __restrict__ WC,
    const float* __restrict__ NSUM, const float* __restrict__ H,
    float* __restrict__ CUMTS, float* __restrict__ INTEG){
  int b=blockIdx.x; int d=threadIdx.x;
  float ats=0.f, acw=0.f;
  for (int n=0;n<NSEQ;++n){
    size_t i=((size_t)b*NSEQ+n)*DIM+d;
    ats += TS[i]; CUMTS[i]=ats;
    acw = fmaf(NSUM[b*NSEQ+n], WC[i], acw);
    INTEG[i] = H[i] + acw;
  }
}

// ====== PM as tiled GEMM: per (f-tile, row-tile, bank k) block ==============
// acc = CUMTS[128 rows x 512] @ Wwrite[k][512 x 128 f-cols], epilogue
// atomicAdd(INTEG, gate*tanh(eta*acc + pm_state)).
__global__ __launch_bounds__(256) void k_pm(const float* __restrict__ CUMTS, const float* __restrict__ GATE,
    const float* __restrict__ pmstate, const float* __restrict__ Wwrite, float* __restrict__ INTEG){
  __shared__ float As[16][132];
  __shared__ float Bs[16][132];
  const int t = threadIdx.x;
  const int colg = t & 15;
  const int rowg = t >> 4;
  const int k    = blockIdx.z;
  const int row0 = blockIdx.y*128;
  const int f0   = blockIdx.x*128;
  const int b    = row0 >> 9;
  const float* Ab = CUMTS + (size_t)row0*DIM;
  const float* Bb = Wwrite + (size_t)k*DIM*DIM;
  float acc[8][8];
#pragma unroll
  for (int i=0;i<8;++i)
#pragma unroll
    for (int j=0;j<8;++j) acc[i][j]=0.f;
  for (int k0=0;k0<DIM;k0+=16){
#pragma unroll
    for (int e=0;e<2;++e){
      int u=t+256*e; int r=u>>2, kq=(u&3)*4;
      float4 a4 = *(const float4*)&Ab[(size_t)r*DIM + k0 + kq];
      As[kq  ][r]=a4.x; As[kq+1][r]=a4.y; As[kq+2][r]=a4.z; As[kq+3][r]=a4.w;
    }
#pragma unroll
    for (int e=0;e<2;++e){
      int u=t+256*e; int kq=u>>5, f4=(u&31)*4;
      float4 b4 = *(const float4*)&Bb[(size_t)(k0+kq)*DIM + f0 + f4];
      *(float4*)&Bs[kq][f4] = b4;
    }
    __syncthreads();
#pragma unroll
    for (int kk=0;kk<16;++kk){
      float av[8], bv[8];
#pragma unroll
      for (int i=0;i<8;++i) av[i]=As[kk][rowg*8+i];
#pragma unroll
      for (int j=0;j<8;++j) bv[j]=Bs[kk][colg+16*j];
#pragma unroll
      for (int i=0;i<8;++i)
#pragma unroll
        for (int j=0;j<8;++j) acc[i][j]=fmaf(av[i],bv[j],acc[i][j]);
    }
    __syncthreads();
  }
  const float* ps = pmstate + ((size_t)(b*NBANK+k))*DIM + f0;
#pragma unroll
  for (int i=0;i<8;++i){
    int row = row0 + rowg*8 + i;
    float g = GATE[(size_t)row*NBANK + k];
    float* orow = INTEG + (size_t)row*DIM + f0;
#pragma unroll
    for (int j=0;j<8;++j){
      int f = colg + 16*j;
      float v = g * tanhf(fmaf(ETA_PM, acc[i][j], ps[f]));
      atomicAdd(&orow[f], v);
    }
  }
}

// ================= final LN =================
__global__ __launch_bounds__(512) void k_lnf(const float* __restrict__ Hp,
    const float* __restrict__ g, const float* __restrict__ bb, float* __restrict__ O){
  __shared__ float red[NC];
  int bn=blockIdx.x; int w=threadIdx.x>>6, l=threadIdx.x&63; int d=threadIdx.x;
  float x = Hp[(size_t)bn*DIM+d];
  float s = wsum(x);
  if (l==0) red[w]=s;
  __syncthreads();
  float tot=0.f; for(int i=0;i<NC;++i) tot+=red[i];
  float mu = tot*(1.f/512.f);
  float dv = x-mu;
  float vs = wsum(dv*dv);
  __syncthreads();
  if (l==0) red[w]=vs;
  __syncthreads();
  float vt=0.f; for(int i=0;i<NC;++i) vt+=red[i];
  O[(size_t)bn*DIM+d] = dv*rsqrtf(vt*(1.f/512.f)+1e-5f)*g[d]+bb[d];
}

// ====== logits GEMM: C[2048,32000] = A[2048,512] @ emb^T (strided cols) =====
__global__ __launch_bounds__(256) void k_gemm(const float* __restrict__ A, const float* __restrict__ Bm,
    float* __restrict__ Cm){
  __shared__ float As[16][132];
  __shared__ float Bs[16][132];
  const int tid = threadIdx.x;
  const int colg = tid & 15;
  const int rowg = tid >> 4;
  const int row0 = blockIdx.y*128;
  const int col0 = blockIdx.x*128;
  float acc[8][8];
#pragma unroll
  for (int i=0;i<8;++i)
#pragma unroll
    for (int j=0;j<8;++j) acc[i][j]=0.f;
  for (int k0=0;k0<DIM;k0+=16){
#pragma unroll
    for (int i=0;i<2;++i){
      int u = tid + 256*i;
      int r = u >> 2;
      int kq = (u & 3)*4;
      float4 a4 = *(const float4*)&A [(size_t)(row0+r)*DIM + k0 + kq];
      As[kq  ][r]=a4.x; As[kq+1][r]=a4.y; As[kq+2][r]=a4.z; As[kq+3][r]=a4.w;
      float4 b4 = *(const float4*)&Bm[(size_t)(col0+r)*DIM + k0 + kq];
      Bs[kq  ][r]=b4.x; Bs[kq+1][r]=b4.y; Bs[kq+2][r]=b4.z; Bs[kq+3][r]=b4.w;
    }
    __syncthreads();
#pragma unroll
    for (int k=0;k<16;++k){
      float av[8], bv[8];
#pragma unroll
      for (int i=0;i<8;++i) av[i]=As[k][rowg*8+i];
#pragma unroll
      for (int j=0;j<8;++j) bv[j]=Bs[k][colg+16*j];   // strided: conflict-free
#pragma unroll
      for (int i=0;i<8;++i)
#pragma unroll
        for (int j=0;j<8;++j) acc[i][j] = fmaf(av[i], bv[j], acc[i][j]);
    }
    __syncthreads();
  }
#pragma unroll
  for (int i=0;i<8;++i){
    size_t rb = (size_t)(row0+rowg*8+i)*VOC + col0;
#pragma unroll
    for (int j=0;j<8;++j) Cm[rb + colg + 16*j] = acc[i][j];
  }
}

// ================= aux loss =================
__global__ __launch_bounds__(256) void k_aux(const float* __restrict__ auxp, float* __restrict__ out){
  __shared__ float red[4];
  float s=0.f;
  for (int i=threadIdx.x;i<NROW;i+=256) s+=auxp[i];
  s = wsum(s);
  int w=threadIdx.x>>6, l=threadIdx.x&63;
  if (l==0) red[w]=s;
  __syncthreads();
  if (threadIdx.x==0){
    float t=red[0]+red[1]+red[2]+red[3];
    out[(size_t)NROW*VOC] = PCM_W * t / (float)(NROW*NC*DC);
  }
}

// ================= host launch =================
extern "C" void kernel_launch(void* const* d_in, const int* in_sizes, int n_in,
                              void* d_out, int out_size, void* d_ws, size_t ws_size,
                              hipStream_t stream){
  const int*   ids    = (const int*)  d_in[0];
  const float* emb    = (const float*)d_in[1];
  const float* pos    = (const float*)d_in[2];
  const float* s1Wv   = (const float*)d_in[3];
  const float* s1Wg   = (const float*)d_in[4];
  const float* s1al   = (const float*)d_in[5];
  const float* s1W1   = (const float*)d_in[6];
  const float* s1W2   = (const float*)d_in[7];
  const float* s1lng  = (const float*)d_in[8];
  const float* s1lnb  = (const float*)d_in[9];
  const float* s3Wv   = (const float*)d_in[10];
  const float* s3Wg   = (const float*)d_in[11];
  const float* s3al   = (const float*)d_in[12];
  const float* s3W1   = (const float*)d_in[13];
  const float* s3W2   = (const float*)d_in[14];
  const float* s3lng  = (const float*)d_in[15];
  const float* s3lnb  = (const float*)d_in[16];
  const float* seedwW = (const float*)d_in[17];
  const float* seedwb = (const float*)d_in[18];
  const float* Wpred  = (const float*)d_in[19];
  const float* bpred  = (const float*)d_in[20];
  const float* Wgain  = (const float*)d_in[21];
  const float* wnovW  = (const float*)d_in[22];
  const float* wnovb  = (const float*)d_in[23];
  const float* Wwrite = (const float*)d_in[24];
  const float* WkeyW  = (const float*)d_in[25];
  const float* pmst   = (const float*)d_in[26];
  const float* slots  = (const float*)d_in[27];
  const float* lnfg   = (const float*)d_in[28];
  const float* lnfb   = (const float*)d_in[29];

  float* ws = (float*)d_ws;
  const size_t U = 1u<<20;        // 1M floats
  float* X     = ws + 0*U;   // aliased: ATT1 (X dead after k_pcm)
  float* H     = ws + 1*U;
  float* Vb    = ws + 2*U;
  float* Gb    = ws + 3*U;
  float* TS    = ws + 4*U;   // aliased: ATT2 (TS dead after k_cum)
  float* SEED  = ws + 5*U;
  float* WC    = ws + 6*U;
  float* CUMTS = ws + 7*U;
  float* INTEG = ws + 8*U;
  float* LNOUT = ws + 9*U;
  float* ATT1  = X;
  float* ATT2  = TS;
  float* tail  = ws + 10*U;
  float* SNORM = tail;                    // 2048
  float* GATE  = SNORM + 2048;            // 16384
  float* NSUM  = GATE + NROW*NBANK;       // 2048
  float* AUXP  = NSUM + NROW;             // 2048
  float* MXB   = AUXP + NROW;             // 16384
  float* WCN   = MXB + NROW*NBANK;        // 2048
  float* GBUF  = WCN + NROW;              // 131072

  float* logits = (float*)d_out;

  k_embed <<<NROW,256,0,stream>>>(ids,emb,pos,X,H);
  k_snorm <<<BSZ*NBANK*NSLOT,64,0,stream>>>(slots,SNORM);
  k_emg   <<<BSZ*NBANK,256,0,stream>>>(slots,GBUF);

  for (int i=0;i<2;++i){
    k_lnvg<<<NC*(NROW/8),512,0,stream>>>(H, s1Wv+i*NC*DC*DC, s1Wg+i*NC*DC*DC,
                                          s1lng+i*DC, s1lnb+i*DC, Vb, Gb);
    k_scan<<<BSZ*NC,512,0,stream>>>(Vb, s1al+i*NC*DC);
    k_mlp <<<NC*(NROW/8),512,0,stream>>>(H, Vb, Gb, s1W1+i*NC*DC*EDIM, s1W2+i*NC*EDIM*DC);
  }

  k_pcm     <<<NROW,512,0,stream>>>(X,H,Wpred,bpred,Wgain,seedwW,seedwb,TS,SEED,WC,WCN,AUXP);
  k_score<1><<<dim3(NBANK,4,BSZ),256,0,stream>>>(WC,  slots,WCN,SNORM,MXB);
  k_gates   <<<NROW,64,0,stream>>>(H,wnovW,wnovb,WkeyW,MXB,GATE,NSUM);
  k_cum     <<<BSZ,512,0,stream>>>(TS,WC,NSUM,H,CUMTS,INTEG);
  k_pm      <<<dim3(DIM/128, NROW/128, NBANK),256,0,stream>>>(CUMTS,GATE,pmst,Wwrite,INTEG);
  k_score<0><<<dim3(NBANK,4,BSZ),256,0,stream>>>(SEED,slots,WCN,SNORM,ATT1);
  k_emscore2<<<dim3(NBANK,4,BSZ),256,0,stream>>>(ATT1,GBUF,ATT2);
  k_empv2   <<<dim3(8,4,BSZ),256,0,stream>>>(ATT2,slots,INTEG);

  for (int i=0;i<2;++i){
    k_lnvg<<<NC*(NROW/8),512,0,stream>>>(INTEG, s3Wv+i*NC*DC*DC, s3Wg+i*NC*DC*DC,
                                          s3lng+i*DC, s3lnb+i*DC, Vb, Gb);
    k_scan<<<BSZ*NC,512,0,stream>>>(Vb, s3al+i*NC*DC);
    k_mlp <<<NC*(NROW/8),512,0,stream>>>(INTEG, Vb, Gb, s3W1+i*NC*DC*EDIM, s3W2+i*NC*EDIM*DC);
  }

  k_lnf <<<NROW,512,0,stream>>>(INTEG,lnfg,lnfb,LNOUT);
  k_gemm<<<dim3(VOC/128, NROW/128),256,0,stream>>>(LNOUT,emb,logits);
  k_aux <<<1,256,0,stream>>>(AUXP,logits);
}